// Round 1
// baseline (246.518 us; speedup 1.0000x reference)
//
#include <hip/hip_runtime.h>

#define NK 256   // IN == OUT == 256

typedef __attribute__((ext_vector_type(8))) short bf16x8;
typedef __attribute__((ext_vector_type(4))) float f32x4;

union BF8 { bf16x8 v; ushort u[8]; uint4 q; };

__device__ inline ushort f2bf(float f) {
    // round-to-nearest-even fp32 -> bf16 (inputs are finite normals)
    uint u = __float_as_uint(f);
    u += 0x7FFFu + ((u >> 16) & 1u);
    return (ushort)(u >> 16);
}

// Block: 512 threads = 8 waves. Wave wv owns rows [blk*128 + wv*16, +16) x all 256 cols.
// LDS: binarized W as bf16, layout [n][k] padded to 264 elems/row (528B stride -> 2-way
// bank aliasing on ds_read_b128, free per m136).
__global__ __launch_bounds__(512, 2) void fused_binlinear(
    const float* __restrict__ x, const float* __restrict__ w, float* __restrict__ out)
{
    __shared__ ushort Bs[256 * 264];   // 132 KB

    const int tid = threadIdx.x;
    const int wv  = tid >> 6;
    const int ln  = tid & 63;
    const int m   = ln & 15;   // MFMA m / n / col lane index
    const int q   = ln >> 4;   // MFMA k-quad / row-quad

    const int row0 = blockIdx.x * 128 + wv * 16;

    // ---- A loads: 16 rows x 256 k, fp32, issued first so they fly during B staging ----
    const float4* xv = (const float4*)(x + (size_t)(row0 + m) * NK + q * 8);
    float4 a0[8], a1[8];
#pragma unroll
    for (int s = 0; s < 8; ++s) { a0[s] = xv[s * 8]; a1[s] = xv[s * 8 + 1]; }

    // ---- stage binarized W into LDS (fold the >0.8 filter in; w is L2/L3-hot) ----
#pragma unroll
    for (int i = 0; i < 16; ++i) {
        int cc = i * 512 + tid;          // 8-element chunk id, 8192 total
        int n  = cc >> 5;
        int kc = cc & 31;
        const float4* wp = (const float4*)(w + n * NK + kc * 8);
        float4 w0 = wp[0], w1 = wp[1];
        uint4 pk;
        pk.x = (w0.x > 0.8f ? 0x00003F80u : 0u) | (w0.y > 0.8f ? 0x3F800000u : 0u);
        pk.y = (w0.z > 0.8f ? 0x00003F80u : 0u) | (w0.w > 0.8f ? 0x3F800000u : 0u);
        pk.z = (w1.x > 0.8f ? 0x00003F80u : 0u) | (w1.y > 0.8f ? 0x3F800000u : 0u);
        pk.w = (w1.z > 0.8f ? 0x00003F80u : 0u) | (w1.w > 0.8f ? 0x3F800000u : 0u);
        *(uint4*)(&Bs[n * 264 + kc * 8]) = pk;
    }
    __syncthreads();

    // ---- convert A to bf16 MFMA fragments: lane holds A[m][k= s*32 + q*8 + j] ----
    bf16x8 fa[8];
#pragma unroll
    for (int s = 0; s < 8; ++s) {
        BF8 t;
        t.u[0] = f2bf(a0[s].x); t.u[1] = f2bf(a0[s].y);
        t.u[2] = f2bf(a0[s].z); t.u[3] = f2bf(a0[s].w);
        t.u[4] = f2bf(a1[s].x); t.u[5] = f2bf(a1[s].y);
        t.u[6] = f2bf(a1[s].z); t.u[7] = f2bf(a1[s].w);
        fa[s] = t.v;
    }

    // ---- MFMA: 8 k-steps x 16 n-tiles; B frag = Bs[n = t*16+m][k = s*32 + q*8 ..] ----
    f32x4 acc[16];
#pragma unroll
    for (int t = 0; t < 16; ++t) acc[t] = (f32x4){0.f, 0.f, 0.f, 0.f};
#pragma unroll
    for (int s = 0; s < 8; ++s) {
#pragma unroll
        for (int t = 0; t < 16; ++t) {
            bf16x8 fb = *(const bf16x8*)(&Bs[(t * 16 + m) * 264 + s * 32 + q * 8]);
            acc[t] = __builtin_amdgcn_mfma_f32_16x16x32_bf16(fa[s], fb, acc[t], 0, 0, 0);
        }
    }

    // ---- fused row-mean: wave holds full rows; C/D layout col=ln&15, row=q*4+r ----
    float rs[4];
#pragma unroll
    for (int r = 0; r < 4; ++r) {
        float s = 0.f;
#pragma unroll
        for (int t = 0; t < 16; ++t) s += acc[t][r];
        rs[r] = s;
    }
#pragma unroll
    for (int r = 0; r < 4; ++r) {
        rs[r] += __shfl_xor(rs[r], 1, 64);
        rs[r] += __shfl_xor(rs[r], 2, 64);
        rs[r] += __shfl_xor(rs[r], 4, 64);
        rs[r] += __shfl_xor(rs[r], 8, 64);
        rs[r] *= (1.0f / 256.0f);
    }

    // ---- store: lane writes col t*16+m of row row0+q*4+r ----
#pragma unroll
    for (int t = 0; t < 16; ++t) {
#pragma unroll
        for (int r = 0; r < 4; ++r) {
            out[(size_t)(row0 + q * 4 + r) * NK + t * 16 + m] = acc[t][r] - rs[r];
        }
    }
}

extern "C" void kernel_launch(void* const* d_in, const int* in_sizes, int n_in,
                              void* d_out, int out_size, void* d_ws, size_t ws_size,
                              hipStream_t stream) {
    const float* x  = (const float*)d_in[0];   // [131072, 256] fp32
    const float* w  = (const float*)d_in[1];   // [256, 256] fp32
    float* out      = (float*)d_out;           // [131072, 256] fp32
    const int M     = in_sizes[0] / NK;        // 131072
    fused_binlinear<<<M / 128, 512, 0, stream>>>(x, w, out);
}